// Round 8
// baseline (30.948 us; speedup 1.0000x reference)
//
#include <hip/hip_runtime.h>
#include <hip/hip_fp16.h>

// Problem constants: N=64, D=4096, E=8192, PER_COL=128;
// col_ids = repeat(arange(E),128) -> column e owns nnz [e*128, e*128+128).
#define NB  64
#define D_  4096
#define E_  8192
#define PC_ 128

#define LOG2E 1.4426950408889634f
#define LN2   0.6931471805599453f

// Identity: out[n,e] = ln( sum_k exp(v_k + x[n,r_k]) ) = ln( sum_k w_k * y[n,r_k] )
// with w = exp(values) (f32), y = exp(x) (f16). All terms positive, f32 sum,
// terms <= e^10 -> no overflow; f16 y rel-err ~5e-4 -> log abs err ~1e-3.
//
// ws layout: y4q = uint2[D_*16]  (512 KiB): y4q[d*16+j] packs y[d][n] for
//                 n = {j, j+16, j+32, j+48} as 4 x f16 (one 8B quad per lane).
//            meta = int2[NNZ]    (8 MiB):   meta[i] = { rows[i], bits(exp(values[i])) }.

// k_prep: blocks [0,64): LDS-tiled transpose of x + exp + 4-row f16 packing.
//         blocks [64,1088): meta interleave (rows + exp(values)), vectorized.
__global__ __launch_bounds__(256) void k_prep(const float* __restrict__ x,
                                              const float* __restrict__ values,
                                              const int*   __restrict__ rows,
                                              uint2* __restrict__ y4q,
                                              int2*  __restrict__ meta) {
    const int b = blockIdx.x;
    if (b < D_ / 64) {
        __shared__ float ld[64][65];            // +1 pad: 2-way alias only
        const int wv = threadIdx.x >> 6, lane = threadIdx.x & 63;
        const int d0 = b * 64;
#pragma unroll
        for (int jj = 0; jj < 16; ++jj) {
            int n = wv + 4 * jj;
            ld[lane][n] = x[n * D_ + d0 + lane];             // coalesced read
        }
        __syncthreads();
        // 64 d x 16 j outputs = 1024 quads; 4 per thread, consecutive addr.
#pragma unroll
        for (int it = 0; it < 4; ++it) {
            int item = it * 256 + threadIdx.x;
            int dd = item >> 4, j = item & 15;
            float e0  = __builtin_amdgcn_exp2f(ld[dd][j]      * LOG2E);
            float e16 = __builtin_amdgcn_exp2f(ld[dd][j + 16] * LOG2E);
            float e32 = __builtin_amdgcn_exp2f(ld[dd][j + 32] * LOG2E);
            float e48 = __builtin_amdgcn_exp2f(ld[dd][j + 48] * LOG2E);
            __half2 h0 = __floats2half2_rn(e0,  e16);        // lo=n(j), hi=n(j+16)
            __half2 h1 = __floats2half2_rn(e32, e48);        // lo=n(j+32), hi=n(j+48)
            uint2 g;
            g.x = *(unsigned*)&h0;
            g.y = *(unsigned*)&h1;
            y4q[(d0 + dd) * 16 + j] = g;                     // 8B coalesced store
        }
    } else {
        // meta: 1024 blocks x 256 threads x 4 nnz = 1M entries.
        int i = (b - D_ / 64) * 1024 + threadIdx.x * 4;
        int4   r4 = *(const int4*)(rows + i);
        float4 v4 = *(const float4*)(values + i);
        int4 s0, s1;
        s0.x = r4.x; s0.y = __float_as_int(__builtin_amdgcn_exp2f(v4.x * LOG2E));
        s0.z = r4.y; s0.w = __float_as_int(__builtin_amdgcn_exp2f(v4.y * LOG2E));
        s1.x = r4.z; s1.y = __float_as_int(__builtin_amdgcn_exp2f(v4.z * LOG2E));
        s1.z = r4.w; s1.w = __float_as_int(__builtin_amdgcn_exp2f(v4.w * LOG2E));
        ((int4*)(meta + i))[0] = s0;                         // 16B aligned (i%4==0)
        ((int4*)(meta + i))[1] = s1;
    }
}

// k_acc: ONE wave per column e. Lane layout: q = lane>>4 (k-slot within a
// group of 4 nnz), j = lane&15 (n-group: this lane owns n = j,j+16,j+32,j+48).
// Per group t (4 nnz): one 8B meta load (lane-shared, L1-hot) gives this
// lane's (row, w); one dwordx2 gather fetches 4 DIFFERENT rows in a single
// instruction (16 lanes per row). 32 groups per column -> 32 gather instrs
// instead of 128: tests the per-instruction vL1D miss-cost theory.
__global__ __launch_bounds__(256, 8) void k_acc(const uint2* __restrict__ y4q,
                                                const int2*  __restrict__ meta,
                                                float* __restrict__ out) {
    const int wv   = threadIdx.x >> 6;
    const int lane = threadIdx.x & 63;
    const int q    = lane >> 4;          // k-slot 0..3
    const int j    = lane & 15;          // n-group
    const int e    = blockIdx.x * 4 + wv;
    const int2* __restrict__ mp = meta + e * PC_;

    float4 acc = make_float4(0.f, 0.f, 0.f, 0.f);
#pragma unroll 8
    for (int t = 0; t < PC_ / 4; ++t) {
        int2  mv = mp[4 * t + q];            // {row, bits(w)} for k = 4t+q
        float vw = __int_as_float(mv.y);
        uint2 g  = y4q[mv.x * 16 + j];       // 4-row packed gather, one instr
        __half2 h0 = *(__half2*)&g.x;
        __half2 h1 = *(__half2*)&g.y;
        float2 f0 = __half22float2(h0);
        float2 f1 = __half22float2(h1);
        acc.x = __builtin_fmaf(vw, f0.x, acc.x);   // n = j
        acc.y = __builtin_fmaf(vw, f0.y, acc.y);   // n = j+16
        acc.z = __builtin_fmaf(vw, f1.x, acc.z);   // n = j+32
        acc.w = __builtin_fmaf(vw, f1.y, acc.w);   // n = j+48
    }
    // Sum the 4 k-slots: lanes {j, j+16q'} hold partials for the same n-set.
    acc.x += __shfl_xor(acc.x, 16); acc.x += __shfl_xor(acc.x, 32);
    acc.y += __shfl_xor(acc.y, 16); acc.y += __shfl_xor(acc.y, 32);
    acc.z += __shfl_xor(acc.z, 16); acc.z += __shfl_xor(acc.z, 32);
    acc.w += __shfl_xor(acc.w, 16); acc.w += __shfl_xor(acc.w, 32);

    if (q == 0) {
        // out[n][E]; scatter store proven neutral (R3).
        out[j        * E_ + e] = LN2 * __builtin_amdgcn_logf(acc.x);
        out[(j + 16) * E_ + e] = LN2 * __builtin_amdgcn_logf(acc.y);
        out[(j + 32) * E_ + e] = LN2 * __builtin_amdgcn_logf(acc.z);
        out[(j + 48) * E_ + e] = LN2 * __builtin_amdgcn_logf(acc.w);
    }
}

extern "C" void kernel_launch(void* const* d_in, const int* in_sizes, int n_in,
                              void* d_out, int out_size, void* d_ws, size_t ws_size,
                              hipStream_t stream) {
    const float* x      = (const float*)d_in[0];
    const float* values = (const float*)d_in[1];
    const int*   rows   = (const int*)d_in[2];
    // d_in[3] = col_ids: structure known (repeat(arange(E),128)) -> unused.
    float* out = (float*)d_out;

    char* ws = (char*)d_ws;
    uint2* y4q  = (uint2*)ws;                      // 512 KiB
    int2*  meta = (int2*)(ws + (512 << 10));       // 8 MiB

    k_prep<<<D_ / 64 + (E_ * PC_) / 1024, 256, 0, stream>>>(x, values, rows, y4q, meta);
    k_acc <<<E_ / 4, 256, 0, stream>>>(y4q, meta, out);
}

// Round 9
// 24.623 us; speedup vs baseline: 1.2569x; 1.2569x over previous
//
#include <hip/hip_runtime.h>

// Problem constants: N=64, D=4096, E=8192, PER_COL=128;
// col_ids = repeat(arange(E),128) -> column e owns nnz [e*128, e*128+128).
#define NB  64
#define D_  4096
#define E_  8192
#define PC_ 128

#define LOG2E 1.4426950408889634f
#define LN2   0.6931471805599453f

// Identity: out[n,e] = ln( sum_k exp(v_k + x[n,r_k]) ) = ln( sum_k w_k * y[n,r_k] )
// with w = exp(values) (f32), y = exp(x) (f16, transposed). Positive terms,
// f32 sum, terms <= e^10 -> no overflow; f16 y rel-err ~5e-4 -> log err ~1e-3.
// ws: y16 = _Float16[D][64] (512 KiB), w = float[NNZ] (4 MiB).

// k_prep (unchanged from R6, proven): blocks [0,64): transpose+exp+f16 pack;
// blocks [64,1088): w = exp(values), float4-vectorized.
__global__ __launch_bounds__(256) void k_prep(const float* __restrict__ x,
                                              const float* __restrict__ values,
                                              _Float16* __restrict__ y16,
                                              float* __restrict__ w) {
    const int wv = threadIdx.x >> 6, lane = threadIdx.x & 63;
    const int b = blockIdx.x;
    if (b < D_ / 64) {
        __shared__ float ld[64][65];
        const int d0 = b * 64;
#pragma unroll
        for (int j = 0; j < 16; ++j) {
            int n = wv + 4 * j;
            ld[lane][n] = x[n * D_ + d0 + lane];
        }
        __syncthreads();
#pragma unroll
        for (int j = 0; j < 16; ++j) {
            int dd = wv + 4 * j;
            y16[(d0 + dd) * NB + lane] =
                (_Float16)__builtin_amdgcn_exp2f(ld[dd][lane] * LOG2E);
        }
    } else {
        int i = (b - D_ / 64) * 1024 + threadIdx.x * 4;
        float4 v = *(const float4*)(values + i);
        float4 o;
        o.x = __builtin_amdgcn_exp2f(v.x * LOG2E);
        o.y = __builtin_amdgcn_exp2f(v.y * LOG2E);
        o.z = __builtin_amdgcn_exp2f(v.z * LOG2E);
        o.w = __builtin_amdgcn_exp2f(v.w * LOG2E);
        *(float4*)(w + i) = o;
    }
}

// k_acc: two waves per column (64 nnz each), lane = batch row n.
// MANUAL 8-DEEP SOFTWARE PIPELINE: named prefetch slots q0..q7 keep 8
// gathers in flight per wave (the compiler was keeping ~1 -> 50 cyc/gather).
// Metadata broadcast via readlane (register-latency, no memory ops in loop).
__global__ __launch_bounds__(256) void k_acc(const _Float16* __restrict__ y16,
                                             const float* __restrict__ w,
                                             const int*   __restrict__ rows,
                                             float* __restrict__ out) {
    __shared__ float part[4][64];
    const int wv   = threadIdx.x >> 6;
    const int lane = threadIdx.x & 63;
    const int col  = wv >> 1;
    const int half = wv & 1;
    const int e    = blockIdx.x * 2 + col;
    const int base = __builtin_amdgcn_readfirstlane(e * PC_ + half * 64);

    const int rbits = rows[base + lane];             // lane k: row_k
    const int wbits = ((const int*)w)[base + lane];  // lane k: bits(w_k)

    const _Float16* __restrict__ yl = y16 + lane;    // per-lane base

    _Float16 q0, q1, q2, q3, q4, q5, q6, q7;
    float s0 = 0.0f, s1 = 0.0f;

#define LOADQ(slot, k) \
    q##slot = yl[((unsigned)__builtin_amdgcn_readlane(rbits, (k))) << 6]
#define USEQ(slot, k, acc) \
    acc = __builtin_fmaf(__int_as_float(__builtin_amdgcn_readlane(wbits, (k))), \
                         (float)q##slot, acc)

    // prologue: fill the ring (8 loads in flight)
    LOADQ(0, 0); LOADQ(1, 1); LOADQ(2, 2); LOADQ(3, 3);
    LOADQ(4, 4); LOADQ(5, 5); LOADQ(6, 6); LOADQ(7, 7);

#define STAGE(B) \
    USEQ(0, B + 0, s0); LOADQ(0, B + 8);  \
    USEQ(1, B + 1, s1); LOADQ(1, B + 9);  \
    USEQ(2, B + 2, s0); LOADQ(2, B + 10); \
    USEQ(3, B + 3, s1); LOADQ(3, B + 11); \
    USEQ(4, B + 4, s0); LOADQ(4, B + 12); \
    USEQ(5, B + 5, s1); LOADQ(5, B + 13); \
    USEQ(6, B + 6, s0); LOADQ(6, B + 14); \
    USEQ(7, B + 7, s1); LOADQ(7, B + 15);

    STAGE(0); STAGE(8); STAGE(16); STAGE(24); STAGE(32); STAGE(40); STAGE(48);

    // tail: drain the ring (k = 56..63), no more loads
    USEQ(0, 56, s0); USEQ(1, 57, s1); USEQ(2, 58, s0); USEQ(3, 59, s1);
    USEQ(4, 60, s0); USEQ(5, 61, s1); USEQ(6, 62, s0); USEQ(7, 63, s1);

#undef LOADQ
#undef USEQ
#undef STAGE

    part[wv][lane] = s0 + s1;
    __syncthreads();

    if (half == 0) {
        float s = part[wv][lane] + part[wv + 1][lane];
        out[lane * E_ + e] = LN2 * __builtin_amdgcn_logf(s);  // scatter (neutral, R3)
    }
}

extern "C" void kernel_launch(void* const* d_in, const int* in_sizes, int n_in,
                              void* d_out, int out_size, void* d_ws, size_t ws_size,
                              hipStream_t stream) {
    const float* x      = (const float*)d_in[0];
    const float* values = (const float*)d_in[1];
    const int*   rows   = (const int*)d_in[2];
    // d_in[3] = col_ids: structure known (repeat(arange(E),128)) -> unused.
    float* out = (float*)d_out;

    char* ws = (char*)d_ws;
    _Float16* y16 = (_Float16*)ws;                 // 512 KiB
    float*    w   = (float*)(ws + (512 << 10));    // 4 MiB

    k_prep<<<D_ / 64 + (E_ * PC_) / 1024, 256, 0, stream>>>(x, values, y16, w);
    k_acc <<<E_ / 2, 256, 0, stream>>>(y16, w, rows, out);
}